// Round 2
// baseline (887.655 us; speedup 1.0000x reference)
//
#include <hip/hip_runtime.h>
#include <math.h>

// ---------------------------------------------------------------------------
// GCNGuard forward: 2x (guard-weights + linear + weighted aggregation)
// Edges arrive sorted by (row, col) [np.unique axis=0], no self loops, unique.
// ---------------------------------------------------------------------------

// One wave per node: inv L2 norm of 128-dim feature row.
__global__ void inv_norm_kernel(const float* __restrict__ x,
                                float* __restrict__ inv_n, int N) {
    int wid  = (blockIdx.x * blockDim.x + threadIdx.x) >> 6;
    int lane = threadIdx.x & 63;
    if (wid >= N) return;
    const float2* xr = (const float2*)(x + (size_t)wid * 128);
    float2 v = xr[lane];
    float s = v.x * v.x + v.y * v.y;
#pragma unroll
    for (int off = 1; off < 64; off <<= 1) s += __shfl_xor(s, off);
    if (lane == 0) {
        float n = sqrtf(s);
        inv_n[wid] = (n == 0.f) ? 1.f : 1.f / n;
    }
}

// Build CSR row_ptr from sorted row[] (one thread per edge, boundary fill).
__global__ void row_ptr_kernel(const int* __restrict__ row,
                               int* __restrict__ row_ptr, int E, int N) {
    int e = blockIdx.x * blockDim.x + threadIdx.x;
    if (e >= E) return;
    int r = row[e];
    if (e == 0) {
        for (int i = 0; i <= r; ++i) row_ptr[i] = 0;
    } else {
        int rp = row[e - 1];
        for (int i = rp + 1; i <= r; ++i) row_ptr[i] = e;
    }
    if (e == E - 1) {
        for (int i = r + 1; i <= N; ++i) row_ptr[i] = E;
    }
}

// One wave per row r: for each edge, cosine sim (row feature hoisted into
// registers), threshold at 0.1, accumulate row_sum and degree in-register.
// Writes: edge_w[e] = thresholded raw sim; inv_rs[r]; self_w[r].
// (normalize+exp deferred to agg kernel -> no store/readback fence needed)
__global__ void guard_kernel(const float* __restrict__ feat,
                             const float* __restrict__ inv_n,
                             const int* __restrict__ col,
                             const int* __restrict__ row_ptr,
                             float* __restrict__ edge_w,
                             float* __restrict__ inv_rs,
                             float* __restrict__ self_w, int N) {
    int r    = (blockIdx.x * blockDim.x + threadIdx.x) >> 6;
    int lane = threadIdx.x & 63;
    if (r >= N) return;
    float inv_r = inv_n[r];
    const float2* fr = (const float2*)(feat + (size_t)r * 128);
    float2 xr = fr[lane];
    xr.x *= inv_r;
    xr.y *= inv_r;
    int e0 = row_ptr[r], e1 = row_ptr[r + 1];
    float row_sum = 0.f;
    int deg = 0;
    for (int e = e0; e < e1; ++e) {
        int c = col[e];
        const float2* fc = (const float2*)(feat + (size_t)c * 128);
        float2 xc = fc[lane];
        float p = xr.x * xc.x + xr.y * xc.y;
#pragma unroll
        for (int off = 1; off < 64; off <<= 1) p += __shfl_xor(p, off);
        float s = p * inv_n[c];        // all lanes hold full dot after butterfly
        s = (s < 0.1f) ? 0.f : s;      // SIM_THRESH
        row_sum += s;
        deg += (s > 0.f) ? 1 : 0;
        if (lane == 0) edge_w[e] = s;  // raw thresholded sim
    }
    if (lane == 0) {
        inv_rs[r] = (row_sum > 0.f) ? (1.f / row_sum) : 1.f;
        self_w[r] = expf(1.f / (float)(deg + 1));
    }
}

// Tiled fp32 GEMM: out[N x M] = A[N x 128] @ W[128 x M] + bias.
// W staged in LDS; 256 threads; block computes 64 rows; 4x4 micro-tile/thread.
template <int M>
__launch_bounds__(256, 2)
__global__ void gemm_kernel(const float* __restrict__ A,
                            const float* __restrict__ W,
                            const float* __restrict__ bias,
                            float* __restrict__ out, int N) {
    __shared__ float Wl[128 * M];
    const int t = threadIdx.x;
    for (int i = t; i < 128 * M; i += 256) Wl[i] = W[i];
    __syncthreads();
    const int tr = t >> 4;   // 0..15 row group
    const int tc = t & 15;   // 0..15 col group
    const int i0 = blockIdx.x * 64 + tr * 4;
    const float4* Arow[4];
#pragma unroll
    for (int q = 0; q < 4; ++q) {
        int rq = i0 + q;
        rq = rq < N ? rq : (N - 1);   // clamp loads; stores are guarded
        Arow[q] = (const float4*)(A + (size_t)rq * 128);
    }
#pragma unroll
    for (int j0i = 0; j0i < M / 64; ++j0i) {
        const int j0 = j0i * 64 + tc * 4;
        float acc[4][4] = {};
        for (int k4 = 0; k4 < 32; ++k4) {
            float4 a[4], w[4];
#pragma unroll
            for (int q = 0; q < 4; ++q) a[q] = Arow[q][k4];
#pragma unroll
            for (int kk = 0; kk < 4; ++kk)
                w[kk] = *(const float4*)&Wl[(k4 * 4 + kk) * M + j0];
#pragma unroll
            for (int q = 0; q < 4; ++q) {
                const float av[4] = {a[q].x, a[q].y, a[q].z, a[q].w};
#pragma unroll
                for (int kk = 0; kk < 4; ++kk) {
                    const float wv[4] = {w[kk].x, w[kk].y, w[kk].z, w[kk].w};
#pragma unroll
                    for (int c = 0; c < 4; ++c) acc[q][c] += av[kk] * wv[c];
                }
            }
        }
        float4 bv = *(const float4*)&bias[j0];
#pragma unroll
        for (int q = 0; q < 4; ++q) {
            if (i0 + q < N) {
                float4 o;
                o.x = acc[q][0] + bv.x;
                o.y = acc[q][1] + bv.y;
                o.z = acc[q][2] + bv.z;
                o.w = acc[q][3] + bv.w;
                *(float4*)&out[(size_t)(i0 + q) * M + j0] = o;
            }
        }
    }
}

// One wave per row: out[r] = sum_e exp(sim*inv_rs)*h[col[e]] + self_w[r]*h[r].
// Dead edges (sim==0) are skipped wave-uniformly (big win in layer 1).
template <int M, bool RELU>
__global__ void agg_kernel(const float* __restrict__ h,
                           const float* __restrict__ edge_w,
                           const float* __restrict__ inv_rs,
                           const float* __restrict__ self_w,
                           const int* __restrict__ col,
                           const int* __restrict__ row_ptr,
                           float* __restrict__ out, int N) {
    int r    = (blockIdx.x * blockDim.x + threadIdx.x) >> 6;
    int lane = threadIdx.x & 63;
    if (r >= N) return;
    int e0 = row_ptr[r], e1 = row_ptr[r + 1];
    float invs = inv_rs[r];
    constexpr int V = M / 64;   // floats per lane (2 for M=128, 1 for M=64)
    float acc[V];
#pragma unroll
    for (int q = 0; q < V; ++q) acc[q] = 0.f;
    for (int e = e0; e < e1; ++e) {
        float s = edge_w[e];
        if (s > 0.f) {                       // wave-uniform branch
            float w = expf(s * invs);
            int c = col[e];
            if constexpr (V == 2) {
                const float2* hc = (const float2*)(h + (size_t)c * M);
                float2 v = hc[lane];
                acc[0] += w * v.x;
                acc[1] += w * v.y;
            } else {
                acc[0] += w * h[(size_t)c * M + lane];
            }
        }
    }
    float sw = self_w[r];
    if constexpr (V == 2) {
        const float2* hr = (const float2*)(h + (size_t)r * M);
        float2 v = hr[lane];
        acc[0] += sw * v.x;
        acc[1] += sw * v.y;
        if (RELU) {
            acc[0] = fmaxf(acc[0], 0.f);
            acc[1] = fmaxf(acc[1], 0.f);
        }
        float2 o = {acc[0], acc[1]};
        ((float2*)(out + (size_t)r * M))[lane] = o;
    } else {
        acc[0] += sw * h[(size_t)r * M + lane];
        if (RELU) acc[0] = fmaxf(acc[0], 0.f);
        out[(size_t)r * M + lane] = acc[0];
    }
}

extern "C" void kernel_launch(void* const* d_in, const int* in_sizes, int n_in,
                              void* d_out, int out_size, void* d_ws,
                              size_t ws_size, hipStream_t stream) {
    const float* x  = (const float*)d_in[0];
    const int* ei   = (const int*)d_in[1];
    const float* W1 = (const float*)d_in[2];
    const float* b1 = (const float*)d_in[3];
    const float* W2 = (const float*)d_in[4];
    const float* b2 = (const float*)d_in[5];
    float* out = (float*)d_out;

    const int D = 128;
    const int H = 128;
    const int N = in_sizes[0] / D;
    const int E = in_sizes[1] / 2;
    (void)H; (void)out_size; (void)n_in; (void)ws_size;

    const int* row = ei;
    const int* col = ei + E;

    // workspace carve-out (256B aligned)
    char* ws = (char*)d_ws;
    size_t off = 0;
    auto alloc = [&](size_t bytes) -> void* {
        void* p = ws + off;
        off = (off + bytes + 255) & ~(size_t)255;
        return p;
    };
    int*   row_ptr = (int*)  alloc((size_t)(N + 1) * sizeof(int));
    float* inv_n   = (float*)alloc((size_t)N * sizeof(float));
    float* edge_w  = (float*)alloc((size_t)E * sizeof(float));
    float* inv_rs  = (float*)alloc((size_t)N * sizeof(float));
    float* self_w  = (float*)alloc((size_t)N * sizeof(float));
    float* hlin    = (float*)alloc((size_t)N * 128 * sizeof(float));
    float* h1      = (float*)alloc((size_t)N * 128 * sizeof(float));

    const int wavesPerBlock = 4;                  // 256 threads
    dim3 blk(256);
    dim3 gridRows((N + wavesPerBlock - 1) / wavesPerBlock);
    dim3 gridE((E + 255) / 256);
    dim3 gridGemm((N + 63) / 64);

    // CSR row_ptr (edges identical for both layers)
    row_ptr_kernel<<<gridE, blk, 0, stream>>>(row, row_ptr, E, N);

    // ---- layer 1 ----
    inv_norm_kernel<<<gridRows, blk, 0, stream>>>(x, inv_n, N);
    gemm_kernel<128><<<gridGemm, blk, 0, stream>>>(x, W1, b1, hlin, N);
    guard_kernel<<<gridRows, blk, 0, stream>>>(x, inv_n, col, row_ptr,
                                               edge_w, inv_rs, self_w, N);
    agg_kernel<128, true><<<gridRows, blk, 0, stream>>>(
        hlin, edge_w, inv_rs, self_w, col, row_ptr, h1, N);

    // ---- layer 2 ----
    inv_norm_kernel<<<gridRows, blk, 0, stream>>>(h1, inv_n, N);
    gemm_kernel<64><<<gridGemm, blk, 0, stream>>>(h1, W2, b2, hlin, N);
    guard_kernel<<<gridRows, blk, 0, stream>>>(h1, inv_n, col, row_ptr,
                                               edge_w, inv_rs, self_w, N);
    agg_kernel<64, false><<<gridRows, blk, 0, stream>>>(
        hlin, edge_w, inv_rs, self_w, col, row_ptr, out, N);
}

// Round 5
// 477.753 us; speedup vs baseline: 1.8580x; 1.8580x over previous
//
#include <hip/hip_runtime.h>
#include <math.h>

// ---------------------------------------------------------------------------
// GCNGuard forward: 2x (guard-weights + linear + weighted aggregation)
// Edges sorted by (row, col) [np.unique axis=0], no self loops, unique.
// Edge kernels use a 4-edges-per-wave / 16-lanes-per-edge layout: shorter
// shuffle chains (4 steps vs 6) and 4-deep gather ILP per wave.
// ---------------------------------------------------------------------------

// 4 nodes per wave, 16 lanes per node: inv L2 norm of 128-dim feature row.
__global__ void inv_norm_kernel(const float* __restrict__ x,
                                float* __restrict__ inv_n, int N) {
    int wave = (blockIdx.x * blockDim.x + threadIdx.x) >> 6;
    int lane = threadIdx.x & 63;
    int sub = lane >> 4, sl = lane & 15;
    int node = wave * 4 + sub;
    if (node >= N) return;                    // whole 16-group exits together
    const float4* xr = (const float4*)(x + (size_t)node * 128);
    float4 a = xr[sl];
    float4 b = xr[16 + sl];
    float s = a.x * a.x + a.y * a.y + a.z * a.z + a.w * a.w
            + b.x * b.x + b.y * b.y + b.z * b.z + b.w * b.w;
#pragma unroll
    for (int off = 1; off < 16; off <<= 1) s += __shfl_xor(s, off);
    if (sl == 0) {
        float n = sqrtf(s);
        inv_n[node] = (n == 0.f) ? 1.f : 1.f / n;
    }
}

// Build CSR row_ptr from sorted row[] (one thread per edge, boundary fill).
__global__ void row_ptr_kernel(const int* __restrict__ row,
                               int* __restrict__ row_ptr, int E, int N) {
    int e = blockIdx.x * blockDim.x + threadIdx.x;
    if (e >= E) return;
    int r = row[e];
    if (e == 0) {
        for (int i = 0; i <= r; ++i) row_ptr[i] = 0;
    } else {
        int rp = row[e - 1];
        for (int i = rp + 1; i <= r; ++i) row_ptr[i] = e;
    }
    if (e == E - 1) {
        for (int i = r + 1; i <= N; ++i) row_ptr[i] = E;
    }
}

// One wave per row r; 4 edges in flight (16 lanes per edge).
// edge_w[e] = thresholded raw sim; inv_rs[r]; self_w[r].
__global__ void guard_kernel(const float* __restrict__ feat,
                             const float* __restrict__ inv_n,
                             const int* __restrict__ col,
                             const int* __restrict__ row_ptr,
                             float* __restrict__ edge_w,
                             float* __restrict__ inv_rs,
                             float* __restrict__ self_w, int N) {
    int r    = (blockIdx.x * blockDim.x + threadIdx.x) >> 6;
    int lane = threadIdx.x & 63;
    int sub  = lane >> 4, sl = lane & 15;
    if (r >= N) return;
    float inv_r = inv_n[r];
    const float4* fr = (const float4*)(feat + (size_t)r * 128);
    float4 xa = fr[sl];        // dims [sl*4, sl*4+4)
    float4 xb = fr[16 + sl];   // dims [64+sl*4, ...)
    xa.x *= inv_r; xa.y *= inv_r; xa.z *= inv_r; xa.w *= inv_r;
    xb.x *= inv_r; xb.y *= inv_r; xb.z *= inv_r; xb.w *= inv_r;

    int e0 = row_ptr[r], e1 = row_ptr[r + 1];
    float row_sum = 0.f, degf = 0.f;
    for (int eb = e0; eb < e1; eb += 4) {
        int  e     = eb + sub;
        bool valid = e < e1;
        int  ei    = valid ? e : (e1 - 1);
        int  c     = col[ei];
        const float4* fc = (const float4*)(feat + (size_t)c * 128);
        float4 ca = fc[sl];
        float4 cb = fc[16 + sl];
        float p = xa.x * ca.x + xa.y * ca.y + xa.z * ca.z + xa.w * ca.w
                + xb.x * cb.x + xb.y * cb.y + xb.z * cb.z + xb.w * cb.w;
#pragma unroll
        for (int off = 1; off < 16; off <<= 1) p += __shfl_xor(p, off);
        float s = p * inv_n[c];
        s = (s < 0.1f) ? 0.f : s;     // SIM_THRESH
        s = valid ? s : 0.f;
        row_sum += s;
        degf += (s > 0.f) ? 1.f : 0.f;
        if (valid && sl == 0) edge_w[e] = s;
    }
    row_sum += __shfl_xor(row_sum, 16);
    row_sum += __shfl_xor(row_sum, 32);
    degf    += __shfl_xor(degf, 16);
    degf    += __shfl_xor(degf, 32);
    if (lane == 0) {
        inv_rs[r] = (row_sum > 0.f) ? (1.f / row_sum) : 1.f;
        self_w[r] = expf(1.f / (degf + 1.f));
    }
}

// Tiled fp32 GEMM: out[N x M] = A[N x 128] @ W[128 x M] + bias.
template <int M>
__launch_bounds__(256, 2)
__global__ void gemm_kernel(const float* __restrict__ A,
                            const float* __restrict__ W,
                            const float* __restrict__ bias,
                            float* __restrict__ out, int N) {
    __shared__ float Wl[128 * M];
    const int t = threadIdx.x;
    for (int i = t; i < 128 * M; i += 256) Wl[i] = W[i];
    __syncthreads();
    const int tr = t >> 4;
    const int tc = t & 15;
    const int i0 = blockIdx.x * 64 + tr * 4;
    const float4* Arow[4];
#pragma unroll
    for (int q = 0; q < 4; ++q) {
        int rq = i0 + q;
        rq = rq < N ? rq : (N - 1);
        Arow[q] = (const float4*)(A + (size_t)rq * 128);
    }
#pragma unroll
    for (int j0i = 0; j0i < M / 64; ++j0i) {
        const int j0 = j0i * 64 + tc * 4;
        float acc[4][4] = {};
        for (int k4 = 0; k4 < 32; ++k4) {
            float4 a[4], w[4];
#pragma unroll
            for (int q = 0; q < 4; ++q) a[q] = Arow[q][k4];
#pragma unroll
            for (int kk = 0; kk < 4; ++kk)
                w[kk] = *(const float4*)&Wl[(k4 * 4 + kk) * M + j0];
#pragma unroll
            for (int q = 0; q < 4; ++q) {
                const float av[4] = {a[q].x, a[q].y, a[q].z, a[q].w};
#pragma unroll
                for (int kk = 0; kk < 4; ++kk) {
                    const float wv[4] = {w[kk].x, w[kk].y, w[kk].z, w[kk].w};
#pragma unroll
                    for (int c = 0; c < 4; ++c) acc[q][c] += av[kk] * wv[c];
                }
            }
        }
        float4 bv = *(const float4*)&bias[j0];
#pragma unroll
        for (int q = 0; q < 4; ++q) {
            if (i0 + q < N) {
                float4 o;
                o.x = acc[q][0] + bv.x;
                o.y = acc[q][1] + bv.y;
                o.z = acc[q][2] + bv.z;
                o.w = acc[q][3] + bv.w;
                *(float4*)&out[(size_t)(i0 + q) * M + j0] = o;
            }
        }
    }
}

// One wave per row; 4 edges in flight, 16 lanes per edge. Branch-free:
// dead edges get w=0 and redirect their gather to the (cache-hot) self row.
template <int M, bool RELU>
__global__ void agg_kernel(const float* __restrict__ h,
                           const float* __restrict__ edge_w,
                           const float* __restrict__ inv_rs,
                           const float* __restrict__ self_w,
                           const int* __restrict__ col,
                           const int* __restrict__ row_ptr,
                           float* __restrict__ out, int N) {
    int r    = (blockIdx.x * blockDim.x + threadIdx.x) >> 6;
    int lane = threadIdx.x & 63;
    int sub  = lane >> 4, sl = lane & 15;
    if (r >= N) return;
    int e0 = row_ptr[r], e1 = row_ptr[r + 1];
    float invs = inv_rs[r];
    constexpr int F = M / 16;    // floats per lane: 8 (M=128) or 4 (M=64)
    float acc[F];
#pragma unroll
    for (int q = 0; q < F; ++q) acc[q] = 0.f;

    for (int eb = e0; eb < e1; eb += 4) {
        int  e     = eb + sub;
        bool valid = e < e1;
        int  ei    = valid ? e : (e1 - 1);
        float s = edge_w[ei];
        int   c = col[ei];
        float w = (valid && s > 0.f) ? expf(s * invs) : 0.f;
        int  ce = (w > 0.f) ? c : r;          // dead edge -> hot self row
        const float4* hc = (const float4*)(h + (size_t)ce * M);
        if constexpr (M == 128) {
            float4 a = hc[sl], b = hc[16 + sl];
            acc[0] += w * a.x; acc[1] += w * a.y;
            acc[2] += w * a.z; acc[3] += w * a.w;
            acc[4] += w * b.x; acc[5] += w * b.y;
            acc[6] += w * b.z; acc[7] += w * b.w;
        } else {
            float4 a = hc[sl];
            acc[0] += w * a.x; acc[1] += w * a.y;
            acc[2] += w * a.z; acc[3] += w * a.w;
        }
    }
#pragma unroll
    for (int q = 0; q < F; ++q) {
        acc[q] += __shfl_xor(acc[q], 16);
        acc[q] += __shfl_xor(acc[q], 32);
    }
    float sw = self_w[r];
    const float4* hr = (const float4*)(h + (size_t)r * M);
    if constexpr (M == 128) {
        float4 a = hr[sl], b = hr[16 + sl];
        acc[0] += sw * a.x; acc[1] += sw * a.y;
        acc[2] += sw * a.z; acc[3] += sw * a.w;
        acc[4] += sw * b.x; acc[5] += sw * b.y;
        acc[6] += sw * b.z; acc[7] += sw * b.w;
    } else {
        float4 a = hr[sl];
        acc[0] += sw * a.x; acc[1] += sw * a.y;
        acc[2] += sw * a.z; acc[3] += sw * a.w;
    }
    if (RELU) {
#pragma unroll
        for (int q = 0; q < F; ++q) acc[q] = fmaxf(acc[q], 0.f);
    }
    if (sub == 0) {
        float4* o4 = (float4*)(out + (size_t)r * M);
        float4 o0 = {acc[0], acc[1], acc[2], acc[3]};
        o4[sl] = o0;
        if constexpr (M == 128) {
            float4 o1 = {acc[4], acc[5], acc[6], acc[7]};
            o4[16 + sl] = o1;
        }
    }
}

extern "C" void kernel_launch(void* const* d_in, const int* in_sizes, int n_in,
                              void* d_out, int out_size, void* d_ws,
                              size_t ws_size, hipStream_t stream) {
    const float* x  = (const float*)d_in[0];
    const int* ei   = (const int*)d_in[1];
    const float* W1 = (const float*)d_in[2];
    const float* b1 = (const float*)d_in[3];
    const float* W2 = (const float*)d_in[4];
    const float* b2 = (const float*)d_in[5];
    float* out = (float*)d_out;

    const int D = 128;
    const int N = in_sizes[0] / D;
    const int E = in_sizes[1] / 2;
    (void)out_size; (void)n_in; (void)ws_size;

    const int* row = ei;
    const int* col = ei + E;

    char* ws = (char*)d_ws;
    size_t off = 0;
    auto alloc = [&](size_t bytes) -> void* {
        void* p = ws + off;
        off = (off + bytes + 255) & ~(size_t)255;
        return p;
    };
    int*   row_ptr = (int*)  alloc((size_t)(N + 1) * sizeof(int));
    float* inv_n   = (float*)alloc((size_t)N * sizeof(float));
    float* edge_w  = (float*)alloc((size_t)E * sizeof(float));
    float* inv_rs  = (float*)alloc((size_t)N * sizeof(float));
    float* self_w  = (float*)alloc((size_t)N * sizeof(float));
    float* hlin    = (float*)alloc((size_t)N * 128 * sizeof(float));
    float* h1      = (float*)alloc((size_t)N * 128 * sizeof(float));

    dim3 blk(256);
    dim3 gridRows((N + 3) / 4);      // 1 wave per row, 4 waves/block
    dim3 gridNorm((N + 15) / 16);    // 4 nodes per wave
    dim3 gridE((E + 255) / 256);
    dim3 gridGemm((N + 63) / 64);

    row_ptr_kernel<<<gridE, blk, 0, stream>>>(row, row_ptr, E, N);

    // ---- layer 1 ----
    inv_norm_kernel<<<gridNorm, blk, 0, stream>>>(x, inv_n, N);
    gemm_kernel<128><<<gridGemm, blk, 0, stream>>>(x, W1, b1, hlin, N);
    guard_kernel<<<gridRows, blk, 0, stream>>>(x, inv_n, col, row_ptr,
                                               edge_w, inv_rs, self_w, N);
    agg_kernel<128, true><<<gridRows, blk, 0, stream>>>(
        hlin, edge_w, inv_rs, self_w, col, row_ptr, h1, N);

    // ---- layer 2 ----
    inv_norm_kernel<<<gridNorm, blk, 0, stream>>>(h1, inv_n, N);
    gemm_kernel<64><<<gridGemm, blk, 0, stream>>>(h1, W2, b2, hlin, N);
    guard_kernel<<<gridRows, blk, 0, stream>>>(h1, inv_n, col, row_ptr,
                                               edge_w, inv_rs, self_w, N);
    agg_kernel<64, false><<<gridRows, blk, 0, stream>>>(
        hlin, edge_w, inv_rs, self_w, col, row_ptr, out, N);
}

// Round 6
// 450.435 us; speedup vs baseline: 1.9707x; 1.0606x over previous
//
#include <hip/hip_runtime.h>
#include <math.h>

// ---------------------------------------------------------------------------
// GCNGuard forward: 2x (guard-weights + linear + weighted aggregation)
// Edges sorted by (row, col) [np.unique axis=0], no self loops, unique.
// Edge kernels: 4 edges per wave, 16 lanes per edge, software-pipelined
// gathers (issue next block's loads before reducing current block) to
// overlap the ~400-600cy gather latency with the shuffle/VALU phase.
// ---------------------------------------------------------------------------

// 4 nodes per wave, 16 lanes per node: inv L2 norm of 128-dim feature row.
__global__ void inv_norm_kernel(const float* __restrict__ x,
                                float* __restrict__ inv_n, int N) {
    int wave = (blockIdx.x * blockDim.x + threadIdx.x) >> 6;
    int lane = threadIdx.x & 63;
    int sub = lane >> 4, sl = lane & 15;
    int node = wave * 4 + sub;
    if (node >= N) return;
    const float4* xr = (const float4*)(x + (size_t)node * 128);
    float4 a = xr[sl];
    float4 b = xr[16 + sl];
    float s = a.x * a.x + a.y * a.y + a.z * a.z + a.w * a.w
            + b.x * b.x + b.y * b.y + b.z * b.z + b.w * b.w;
#pragma unroll
    for (int off = 1; off < 16; off <<= 1) s += __shfl_xor(s, off);
    if (sl == 0) {
        float n = sqrtf(s);
        inv_n[node] = (n == 0.f) ? 1.f : 1.f / n;
    }
}

// Build CSR row_ptr from sorted row[] (one thread per edge, boundary fill).
__global__ void row_ptr_kernel(const int* __restrict__ row,
                               int* __restrict__ row_ptr, int E, int N) {
    int e = blockIdx.x * blockDim.x + threadIdx.x;
    if (e >= E) return;
    int r = row[e];
    if (e == 0) {
        for (int i = 0; i <= r; ++i) row_ptr[i] = 0;
    } else {
        int rp = row[e - 1];
        for (int i = rp + 1; i <= r; ++i) row_ptr[i] = e;
    }
    if (e == E - 1) {
        for (int i = r + 1; i <= N; ++i) row_ptr[i] = E;
    }
}

// One wave per row r; 4 edges in flight (16 lanes per edge); depth-1
// software pipeline: next block's feature gathers issue before the current
// block's shuffle-reduce consumes its values. Tail loads clamp to e1-1
// (always in-range, branch-free loop body).
__global__ void guard_kernel(const float* __restrict__ feat,
                             const float* __restrict__ inv_n,
                             const int* __restrict__ col,
                             const int* __restrict__ row_ptr,
                             float* __restrict__ edge_w,
                             float* __restrict__ inv_rs,
                             float* __restrict__ self_w, int N) {
    int r    = (blockIdx.x * blockDim.x + threadIdx.x) >> 6;
    int lane = threadIdx.x & 63;
    int sub  = lane >> 4, sl = lane & 15;
    if (r >= N) return;
    float inv_r = inv_n[r];
    const float4* fr = (const float4*)(feat + (size_t)r * 128);
    float4 xa = fr[sl];
    float4 xb = fr[16 + sl];
    xa.x *= inv_r; xa.y *= inv_r; xa.z *= inv_r; xa.w *= inv_r;
    xb.x *= inv_r; xb.y *= inv_r; xb.z *= inv_r; xb.w *= inv_r;

    int e0 = row_ptr[r], e1 = row_ptr[r + 1];
    float row_sum = 0.f, degf = 0.f;
    if (e0 < e1) {
        // prologue: issue block 0
        int  e  = e0 + sub;
        bool vc = e < e1;
        int  ei = vc ? e : (e1 - 1);
        int  cc = col[ei];
        const float4* fc = (const float4*)(feat + (size_t)cc * 128);
        float4 ca  = fc[sl];
        float4 cb  = fc[16 + sl];
        float  icc = inv_n[cc];
        for (int eb = e0; eb < e1; eb += 4) {
            // issue next block (clamped; harmless duplicate loads past end)
            int  en  = eb + 4 + sub;
            bool vn  = en < e1;
            int  ein = vn ? en : (e1 - 1);
            int  cn  = col[ein];
            const float4* fn = (const float4*)(feat + (size_t)cn * 128);
            float4 na  = fn[sl];
            float4 nb  = fn[16 + sl];
            float  icn = inv_n[cn];
            // process current block
            float p = xa.x * ca.x + xa.y * ca.y + xa.z * ca.z + xa.w * ca.w
                    + xb.x * cb.x + xb.y * cb.y + xb.z * cb.z + xb.w * cb.w;
#pragma unroll
            for (int off = 1; off < 16; off <<= 1) p += __shfl_xor(p, off);
            float s = p * icc;
            s = (s < 0.1f) ? 0.f : s;     // SIM_THRESH
            s = vc ? s : 0.f;
            row_sum += s;
            degf += (s > 0.f) ? 1.f : 0.f;
            if (vc && sl == 0) edge_w[eb + sub] = s;
            // rotate
            vc = vn; ca = na; cb = nb; icc = icn;
        }
    }
    row_sum += __shfl_xor(row_sum, 16);
    row_sum += __shfl_xor(row_sum, 32);
    degf    += __shfl_xor(degf, 16);
    degf    += __shfl_xor(degf, 32);
    if (lane == 0) {
        inv_rs[r] = (row_sum > 0.f) ? (1.f / row_sum) : 1.f;
        self_w[r] = expf(1.f / (degf + 1.f));
    }
}

// Tiled fp32 GEMM: out[N x M] = A[N x 128] @ W[128 x M] + bias.
template <int M>
__launch_bounds__(256, 2)
__global__ void gemm_kernel(const float* __restrict__ A,
                            const float* __restrict__ W,
                            const float* __restrict__ bias,
                            float* __restrict__ out, int N) {
    __shared__ float Wl[128 * M];
    const int t = threadIdx.x;
    for (int i = t; i < 128 * M; i += 256) Wl[i] = W[i];
    __syncthreads();
    const int tr = t >> 4;
    const int tc = t & 15;
    const int i0 = blockIdx.x * 64 + tr * 4;
    const float4* Arow[4];
#pragma unroll
    for (int q = 0; q < 4; ++q) {
        int rq = i0 + q;
        rq = rq < N ? rq : (N - 1);
        Arow[q] = (const float4*)(A + (size_t)rq * 128);
    }
#pragma unroll
    for (int j0i = 0; j0i < M / 64; ++j0i) {
        const int j0 = j0i * 64 + tc * 4;
        float acc[4][4] = {};
        for (int k4 = 0; k4 < 32; ++k4) {
            float4 a[4], w[4];
#pragma unroll
            for (int q = 0; q < 4; ++q) a[q] = Arow[q][k4];
#pragma unroll
            for (int kk = 0; kk < 4; ++kk)
                w[kk] = *(const float4*)&Wl[(k4 * 4 + kk) * M + j0];
#pragma unroll
            for (int q = 0; q < 4; ++q) {
                const float av[4] = {a[q].x, a[q].y, a[q].z, a[q].w};
#pragma unroll
                for (int kk = 0; kk < 4; ++kk) {
                    const float wv[4] = {w[kk].x, w[kk].y, w[kk].z, w[kk].w};
#pragma unroll
                    for (int c = 0; c < 4; ++c) acc[q][c] += av[kk] * wv[c];
                }
            }
        }
        float4 bv = *(const float4*)&bias[j0];
#pragma unroll
        for (int q = 0; q < 4; ++q) {
            if (i0 + q < N) {
                float4 o;
                o.x = acc[q][0] + bv.x;
                o.y = acc[q][1] + bv.y;
                o.z = acc[q][2] + bv.z;
                o.w = acc[q][3] + bv.w;
                *(float4*)&out[(size_t)(i0 + q) * M + j0] = o;
            }
        }
    }
}

// One wave per row; 4 edges in flight, 16 lanes per edge; depth-2 pipeline:
// s/col prefetched 2 blocks ahead, h-gather issued 1 block ahead. Dead edges
// (s==0) redirect gather to the cache-hot self row with weight 0.
template <int M, bool RELU>
__global__ void agg_kernel(const float* __restrict__ h,
                           const float* __restrict__ edge_w,
                           const float* __restrict__ inv_rs,
                           const float* __restrict__ self_w,
                           const int* __restrict__ col,
                           const int* __restrict__ row_ptr,
                           float* __restrict__ out, int N) {
    int r    = (blockIdx.x * blockDim.x + threadIdx.x) >> 6;
    int lane = threadIdx.x & 63;
    int sub  = lane >> 4, sl = lane & 15;
    if (r >= N) return;
    int e0 = row_ptr[r], e1 = row_ptr[r + 1];
    float invs = inv_rs[r];
    constexpr int F = M / 16;    // floats per lane: 8 (M=128) or 4 (M=64)
    float acc[F];
#pragma unroll
    for (int q = 0; q < F; ++q) acc[q] = 0.f;

    if (e0 < e1) {
        // stage block 0: s/c + gather issued
        int  ea  = e0 + sub;
        bool v0  = ea < e1;
        int  ei0 = v0 ? ea : (e1 - 1);
        float s0 = edge_w[ei0];
        int   c0 = col[ei0];
        int  ce0 = (v0 && s0 > 0.f) ? c0 : r;
        const float4* h0p = (const float4*)(h + (size_t)ce0 * M);
        float4 ha0 = h0p[sl];
        float4 hb0;
        if constexpr (M == 128) hb0 = h0p[16 + sl];
        // stage block 1: s/c issued
        int  eb1 = e0 + 4 + sub;
        bool v1  = eb1 < e1;
        int  ei1 = v1 ? eb1 : (e1 - 1);
        float s1 = edge_w[ei1];
        int   c1 = col[ei1];

        for (int eb = e0; eb < e1; eb += 4) {
            // issue s/c for block i+2 (clamped)
            int  en  = eb + 8 + sub;
            bool v2  = en < e1;
            int  ei2 = v2 ? en : (e1 - 1);
            float s2 = edge_w[ei2];
            int   c2 = col[ei2];
            // issue gather for block i+1
            int ce1 = (v1 && s1 > 0.f) ? c1 : r;
            const float4* h1p = (const float4*)(h + (size_t)ce1 * M);
            float4 ha1 = h1p[sl];
            float4 hb1;
            if constexpr (M == 128) hb1 = h1p[16 + sl];
            // process block i
            float w = (v0 && s0 > 0.f) ? __expf(s0 * invs) : 0.f;
            acc[0] += w * ha0.x; acc[1] += w * ha0.y;
            acc[2] += w * ha0.z; acc[3] += w * ha0.w;
            if constexpr (M == 128) {
                acc[4] += w * hb0.x; acc[5] += w * hb0.y;
                acc[6] += w * hb0.z; acc[7] += w * hb0.w;
            }
            // rotate
            v0 = v1; s0 = s1; ha0 = ha1;
            if constexpr (M == 128) hb0 = hb1;
            v1 = v2; s1 = s2; c1 = c2;
        }
    }
#pragma unroll
    for (int q = 0; q < F; ++q) {
        acc[q] += __shfl_xor(acc[q], 16);
        acc[q] += __shfl_xor(acc[q], 32);
    }
    float sw = self_w[r];
    const float4* hr = (const float4*)(h + (size_t)r * M);
    if constexpr (M == 128) {
        float4 a = hr[sl], b = hr[16 + sl];
        acc[0] += sw * a.x; acc[1] += sw * a.y;
        acc[2] += sw * a.z; acc[3] += sw * a.w;
        acc[4] += sw * b.x; acc[5] += sw * b.y;
        acc[6] += sw * b.z; acc[7] += sw * b.w;
    } else {
        float4 a = hr[sl];
        acc[0] += sw * a.x; acc[1] += sw * a.y;
        acc[2] += sw * a.z; acc[3] += sw * a.w;
    }
    if (RELU) {
#pragma unroll
        for (int q = 0; q < F; ++q) acc[q] = fmaxf(acc[q], 0.f);
    }
    if (sub == 0) {
        float4* o4 = (float4*)(out + (size_t)r * M);
        float4 o0 = {acc[0], acc[1], acc[2], acc[3]};
        o4[sl] = o0;
        if constexpr (M == 128) {
            float4 o1 = {acc[4], acc[5], acc[6], acc[7]};
            o4[16 + sl] = o1;
        }
    }
}

extern "C" void kernel_launch(void* const* d_in, const int* in_sizes, int n_in,
                              void* d_out, int out_size, void* d_ws,
                              size_t ws_size, hipStream_t stream) {
    const float* x  = (const float*)d_in[0];
    const int* ei   = (const int*)d_in[1];
    const float* W1 = (const float*)d_in[2];
    const float* b1 = (const float*)d_in[3];
    const float* W2 = (const float*)d_in[4];
    const float* b2 = (const float*)d_in[5];
    float* out = (float*)d_out;

    const int D = 128;
    const int N = in_sizes[0] / D;
    const int E = in_sizes[1] / 2;
    (void)out_size; (void)n_in; (void)ws_size;

    const int* row = ei;
    const int* col = ei + E;

    char* ws = (char*)d_ws;
    size_t off = 0;
    auto alloc = [&](size_t bytes) -> void* {
        void* p = ws + off;
        off = (off + bytes + 255) & ~(size_t)255;
        return p;
    };
    int*   row_ptr = (int*)  alloc((size_t)(N + 1) * sizeof(int));
    float* inv_n   = (float*)alloc((size_t)N * sizeof(float));
    float* edge_w  = (float*)alloc((size_t)E * sizeof(float));
    float* inv_rs  = (float*)alloc((size_t)N * sizeof(float));
    float* self_w  = (float*)alloc((size_t)N * sizeof(float));
    float* hlin    = (float*)alloc((size_t)N * 128 * sizeof(float));
    float* h1      = (float*)alloc((size_t)N * 128 * sizeof(float));

    dim3 blk(256);
    dim3 gridRows((N + 3) / 4);      // 1 wave per row, 4 waves/block
    dim3 gridNorm((N + 15) / 16);    // 4 nodes per wave
    dim3 gridE((E + 255) / 256);
    dim3 gridGemm((N + 63) / 64);

    row_ptr_kernel<<<gridE, blk, 0, stream>>>(row, row_ptr, E, N);

    // ---- layer 1 ----
    inv_norm_kernel<<<gridNorm, blk, 0, stream>>>(x, inv_n, N);
    gemm_kernel<128><<<gridGemm, blk, 0, stream>>>(x, W1, b1, hlin, N);
    guard_kernel<<<gridRows, blk, 0, stream>>>(x, inv_n, col, row_ptr,
                                               edge_w, inv_rs, self_w, N);
    agg_kernel<128, true><<<gridRows, blk, 0, stream>>>(
        hlin, edge_w, inv_rs, self_w, col, row_ptr, h1, N);

    // ---- layer 2 ----
    inv_norm_kernel<<<gridNorm, blk, 0, stream>>>(h1, inv_n, N);
    gemm_kernel<64><<<gridGemm, blk, 0, stream>>>(h1, W2, b2, hlin, N);
    guard_kernel<<<gridRows, blk, 0, stream>>>(h1, inv_n, col, row_ptr,
                                               edge_w, inv_rs, self_w, N);
    agg_kernel<64, false><<<gridRows, blk, 0, stream>>>(
        hlin, edge_w, inv_rs, self_w, col, row_ptr, out, N);
}